// Round 1
// baseline (704.080 us; speedup 1.0000x reference)
//
#include <hip/hip_runtime.h>
#include <stdint.h>

#define BATCH 2
#define NPTS  4096
#define KNBR  32
#define TOKC  128

// ---------------- workspace layout (bytes) ----------------
// idx : int  [B*N*K]    off 0         size 1,048,576
// F   : float[B*N*128]  off 1,048,576 size 4,194,304   (feat_j @ W1[0:64])
// A   : float[B*N*128]  off 5,242,880 size 4,194,304   (abs_pe @ W1[91:187] + b1)
// gmax: uint [B*128]    off 9,437,184 size 1,024
#define OFF_F    1048576
#define OFF_A    5242880
#define OFF_GMAX 9437184

__device__ __forceinline__ unsigned int fkey(float f) {
    unsigned int u = __float_as_uint(f);
    return (u & 0x80000000u) ? ~u : (u | 0x80000000u);
}
__device__ __forceinline__ float funkey(unsigned int k) {
    return __uint_as_float((k & 0x80000000u) ? (k ^ 0x80000000u) : ~k);
}

// ---------------- neighbor search: one wave per point ----------------
__global__ __launch_bounds__(256) void k_search(const float* __restrict__ xyz,
                                                int* __restrict__ oidx) {
    int wave = (blockIdx.x * 256 + threadIdx.x) >> 6;   // 0..8191
    int lane = threadIdx.x & 63;
    int b = wave >> 12;
    int n = wave & (NPTS - 1);
    const float* xb = xyz + (size_t)b * NPTS * 3;
    float cx = xb[n * 3 + 0], cy = xb[n * 3 + 1], cz = xb[n * 3 + 2];
    const float R2 = 0.0256f;     // float(0.16*0.16 computed in double), matches ref
    int cnt = 0;
    int first = 0;
    int* out = oidx + (size_t)wave * KNBR;
    for (int base = 0; base < NPTS; base += 64) {
        #pragma clang fp contract(off)
        int j = base + lane;
        float px = xb[j * 3 + 0], py = xb[j * 3 + 1], pz = xb[j * 3 + 2];
        float dx = px - cx, dy = py - cy, dz = pz - cz;
        float d2 = (dx * dx + dy * dy) + dz * dz;   // same order as numpy, no fma
        bool hit = d2 <= R2;
        unsigned long long m = __ballot(hit);
        if (cnt == 0 && m) first = base + (int)__builtin_ctzll(m);
        if (hit) {
            int pos = cnt + (int)__popcll(m & ((1ull << lane) - 1ull));
            if (pos < KNBR) out[pos] = j;
        }
        cnt += (int)__popcll(m);
        if (cnt >= KNBR) break;
    }
    if (lane >= cnt && lane < KNBR) out[lane] = first;  // pad with first hit
}

// ---------------- precompute F[j] and A[n] (8 points / block) ----------------
__global__ __launch_bounds__(256) void k_prep(const float* __restrict__ xyz,
                                              const float* __restrict__ feat,
                                              const float* __restrict__ W1,
                                              const float* __restrict__ b1,
                                              float* __restrict__ Fw,
                                              float* __restrict__ Aw) {
    __shared__ float featL[8 * 64];
    __shared__ float peL[8 * 96];
    int t = threadIdx.x;
    int g0 = blockIdx.x * 8;   // global point index b*N+n
    featL[t]       = feat[(size_t)g0 * 64 + t];
    featL[t + 256] = feat[(size_t)g0 * 64 + t + 256];
    if (t < 96) {
        int a = t >> 5, i = t & 31, fi = i & 15;
        float fr = expf(-0.6140226914650789f * (float)fi);  // ln(1e4)/15
        for (int q = 0; q < 8; q++) {
            float x = xyz[(size_t)(g0 + q) * 3 + a];
            float ang = x * fr;
            peL[q * 96 + t] = (i < 16) ? sinf(ang) : cosf(ang);
        }
    }
    __syncthreads();
    int c = t & 127, qh = t >> 7;   // qh in {0,1}, 4 points each
    float fa[4] = {0.f, 0.f, 0.f, 0.f};
    float aa[4] = {0.f, 0.f, 0.f, 0.f};
    for (int f = 0; f < 64; f++) {
        float w = W1[f * TOKC + c];
        #pragma unroll
        for (int q = 0; q < 4; q++) fa[q] += featL[(qh * 4 + q) * 64 + f] * w;
    }
    for (int d = 0; d < 96; d++) {
        float w = W1[(91 + d) * TOKC + c];
        #pragma unroll
        for (int q = 0; q < 4; q++) aa[q] += peL[(qh * 4 + q) * 96 + d] * w;
    }
    float bb = b1[c];
    for (int q = 0; q < 4; q++) {
        size_t g = (size_t)(g0 + qh * 4 + q);
        Fw[g * TOKC + c] = fa[q];
        Aw[g * TOKC + c] = aa[q] + bb;
    }
}

// ---------------- main: per (2-point, 64-pair) block, both MLP layers + max ----------------
__global__ __launch_bounds__(256, 2) void k_main(const float* __restrict__ xyz,
                                                 const float* __restrict__ W1,
                                                 const float* __restrict__ W2,
                                                 const int* __restrict__ idxw,
                                                 const float* __restrict__ Fw,
                                                 const float* __restrict__ Aw,
                                                 unsigned int* __restrict__ gmax) {
    __shared__ __align__(16) float h1t[128 * 64];          // [ch1][pair] 32 KB
    __shared__ __align__(16) float uni[27 * 64 + 27 * 128]; // phase1: xin_t | w1l; phase2: w2 chunk
    __shared__ __align__(16) float arow[2 * 128];
    __shared__ int jidxL[64];

    int t = threadIdx.x;
    int b = blockIdx.x >> 11;
    int n0 = (blockIdx.x & 2047) * 2;
    size_t gp0 = (size_t)b * NPTS + n0;

    if (t < 64) jidxL[t] = idxw[gp0 * KNBR + t];
    arow[t] = Aw[gp0 * TOKC + t];   // 2 contiguous rows
    {   // stage W1 rows 64..90 (rel part), 3456 floats, contiguous in source
        const float* src = W1 + 64 * TOKC;
        float* dst = uni + 27 * 64;
        for (int v = t; v < 27 * 128; v += 256) dst[v] = src[v];
    }
    __syncthreads();

    // build xin_t[27][64]: rel xyz + 24-dim rel PE, one thread per pair
    if (t < 64) {
        int p = t;
        int n = n0 + (p >> 5);
        int j = jidxL[p];
        const float* xb = xyz + (size_t)b * NPTS * 3;
        float rx = xb[j * 3 + 0] - xb[n * 3 + 0];
        float ry = xb[j * 3 + 1] - xb[n * 3 + 1];
        float rz = xb[j * 3 + 2] - xb[n * 3 + 2];
        float* xin = uni;
        xin[0 * 64 + p] = rx; xin[1 * 64 + p] = ry; xin[2 * 64 + p] = rz;
        float r3[3] = {rx, ry, rz};
        #pragma unroll
        for (int a = 0; a < 3; a++) {
            #pragma unroll
            for (int fi = 0; fi < 4; fi++) {
                float fr = expf(-3.070113457325395f * (float)fi);  // ln(1e4)/3
                float ang = r3[a] * fr;
                xin[(3 + a * 8 + fi) * 64 + p]     = sinf(ang);
                xin[(3 + a * 8 + 4 + fi) * 64 + p] = cosf(ang);
            }
        }
    }
    __syncthreads();

    // thread mapping: pt = t&15 -> 4 pairs, ct = t>>4 -> 8 channels.
    // within a wave only 4 distinct ct -> B-reads broadcast; A-reads 2-way (free).
    int pt = t & 15, ct = t >> 4;
    int p0 = pt * 4, c0 = ct * 8;

    float acc[4][8];
    #pragma unroll
    for (int i = 0; i < 4; i++)
        #pragma unroll
        for (int jj = 0; jj < 8; jj++) acc[i][jj] = 0.f;

    const float* xin = uni;
    const float* w1l = uni + 27 * 64;
    for (int d = 0; d < 27; d++) {
        float4 a4 = *(const float4*)&xin[d * 64 + p0];
        float4 b0 = *(const float4*)&w1l[d * 128 + c0];
        float4 b1v = *(const float4*)&w1l[d * 128 + c0 + 4];
        float av[4] = {a4.x, a4.y, a4.z, a4.w};
        float bv[8] = {b0.x, b0.y, b0.z, b0.w, b1v.x, b1v.y, b1v.z, b1v.w};
        #pragma unroll
        for (int i = 0; i < 4; i++)
            #pragma unroll
            for (int jj = 0; jj < 8; jj++) acc[i][jj] += av[i] * bv[jj];
    }

    // epilogue 1: + F[j] + A[n], relu, write h1t transposed
    float hreg[8][4];
    #pragma unroll
    for (int i = 0; i < 4; i++) {
        int p = p0 + i;
        int q = p >> 5;
        int j = jidxL[p];
        const float* Fr = Fw + ((size_t)b * NPTS + j) * TOKC + c0;
        float4 f0 = *(const float4*)&Fr[0];
        float4 f1 = *(const float4*)&Fr[4];
        float4 a0 = *(const float4*)&arow[q * 128 + c0];
        float4 a1 = *(const float4*)&arow[q * 128 + c0 + 4];
        float fv[8] = {f0.x + a0.x, f0.y + a0.y, f0.z + a0.z, f0.w + a0.w,
                       f1.x + a1.x, f1.y + a1.y, f1.z + a1.z, f1.w + a1.w};
        #pragma unroll
        for (int jj = 0; jj < 8; jj++)
            hreg[jj][i] = fmaxf(acc[i][jj] + fv[jj], 0.f);
    }
    #pragma unroll
    for (int jj = 0; jj < 8; jj++) {
        float4 v = make_float4(hreg[jj][0], hreg[jj][1], hreg[jj][2], hreg[jj][3]);
        *(float4*)&h1t[(c0 + jj) * 64 + p0] = v;
    }

    // phase 2: h2 = h1 @ W2, K=128 in chunks of 32 staged in LDS (aliases uni)
    float acc2[4][8];
    #pragma unroll
    for (int i = 0; i < 4; i++)
        #pragma unroll
        for (int jj = 0; jj < 8; jj++) acc2[i][jj] = 0.f;

    float* w2c = uni;
    for (int k0 = 0; k0 < 128; k0 += 32) {
        __syncthreads();   // also publishes h1t / retires xin,w1l on first iter
        for (int v = t; v < 32 * 128; v += 256) w2c[v] = W2[k0 * TOKC + v];
        __syncthreads();
        for (int kk = 0; kk < 32; kk++) {
            float4 a4 = *(const float4*)&h1t[(k0 + kk) * 64 + p0];
            float4 b0 = *(const float4*)&w2c[kk * 128 + c0];
            float4 b1v = *(const float4*)&w2c[kk * 128 + c0 + 4];
            float av[4] = {a4.x, a4.y, a4.z, a4.w};
            float bv[8] = {b0.x, b0.y, b0.z, b0.w, b1v.x, b1v.y, b1v.z, b1v.w};
            #pragma unroll
            for (int i = 0; i < 4; i++)
                #pragma unroll
                for (int jj = 0; jj < 8; jj++) acc2[i][jj] += av[i] * bv[jj];
        }
    }

    // max over this thread's 4 pairs, then over the 16 pt-lanes, then atomicMax
    float m8[8];
    #pragma unroll
    for (int jj = 0; jj < 8; jj++)
        m8[jj] = fmaxf(fmaxf(acc2[0][jj], acc2[1][jj]), fmaxf(acc2[2][jj], acc2[3][jj]));
    #pragma unroll
    for (int off = 1; off < 16; off <<= 1)
        #pragma unroll
        for (int jj = 0; jj < 8; jj++)
            m8[jj] = fmaxf(m8[jj], __shfl_xor(m8[jj], off, 16));
    if ((t & 15) == 0) {
        #pragma unroll
        for (int jj = 0; jj < 8; jj++)
            atomicMax(&gmax[b * TOKC + c0 + jj], fkey(m8[jj]));
    }
}

// ---------------- final tiny MLP: g -> relu(g@W3+b3) -> @W4+b4 ----------------
__global__ __launch_bounds__(128) void k_final(const unsigned int* __restrict__ gmax,
                                               const float* __restrict__ b2,
                                               const float* __restrict__ W3,
                                               const float* __restrict__ b3,
                                               const float* __restrict__ W4,
                                               const float* __restrict__ b4,
                                               float* __restrict__ out) {
    __shared__ float gl[128], sl[128];
    int b = blockIdx.x, c = threadIdx.x;
    gl[c] = funkey(gmax[b * TOKC + c]) + b2[c];   // b2 folded here (max is per-channel)
    __syncthreads();
    float s = b3[c];
    for (int k = 0; k < 128; k++) s += gl[k] * W3[k * TOKC + c];
    sl[c] = fmaxf(s, 0.f);
    __syncthreads();
    float o = b4[c];
    for (int k = 0; k < 128; k++) o += sl[k] * W4[k * TOKC + c];
    out[b * TOKC + c] = o;
}

extern "C" void kernel_launch(void* const* d_in, const int* in_sizes, int n_in,
                              void* d_out, int out_size, void* d_ws, size_t ws_size,
                              hipStream_t stream) {
    const float* xyz  = (const float*)d_in[0];
    const float* feat = (const float*)d_in[1];
    const float* W1   = (const float*)d_in[2];
    const float* b1   = (const float*)d_in[3];
    const float* W2   = (const float*)d_in[4];
    const float* b2   = (const float*)d_in[5];
    const float* W3   = (const float*)d_in[6];
    const float* b3   = (const float*)d_in[7];
    const float* W4   = (const float*)d_in[8];
    const float* b4   = (const float*)d_in[9];

    char* ws = (char*)d_ws;
    int*          idxw = (int*)ws;
    float*        Fw   = (float*)(ws + OFF_F);
    float*        Aw   = (float*)(ws + OFF_A);
    unsigned int* gmax = (unsigned int*)(ws + OFF_GMAX);

    hipMemsetAsync(gmax, 0, BATCH * TOKC * sizeof(unsigned int), stream);
    k_search<<<dim3((BATCH * NPTS) / 4), dim3(256), 0, stream>>>(xyz, idxw);
    k_prep<<<dim3((BATCH * NPTS) / 8), dim3(256), 0, stream>>>(xyz, feat, W1, b1, Fw, Aw);
    k_main<<<dim3(BATCH * (NPTS / 2)), dim3(256), 0, stream>>>(xyz, W1, W2, idxw, Fw, Aw, gmax);
    k_final<<<dim3(BATCH), dim3(128), 0, stream>>>(gmax, b2, W3, b3, W4, b4, (float*)d_out);
}

// Round 2
// 221.441 us; speedup vs baseline: 3.1795x; 3.1795x over previous
//
#include <hip/hip_runtime.h>
#include <stdint.h>

#define BATCH 2
#define NPTS  4096
#define KNBR  32
#define TOKC  128

typedef _Float16 half8 __attribute__((ext_vector_type(8)));
typedef _Float16 half4 __attribute__((ext_vector_type(4)));
typedef float    f32x4 __attribute__((ext_vector_type(4)));

// ---------------- workspace layout (bytes) ----------------
// idx : int      [2*4096*32]   @ 0        (1 MB)
// Fh  : _Float16 [2*4096*128]  @ 1 MB     (2 MB)   feat_j @ W1[0:64]
// Ah  : _Float16 [2*4096*128]  @ 3 MB     (2 MB)   abs_pe @ W1[91:187] + b1
// gmax: uint     [2*128]       @ 5 MB
#define OFF_FH   (1u << 20)
#define OFF_AH   (3u << 20)
#define OFF_GMAX (5u << 20)

__device__ __forceinline__ unsigned int fkey(float f) {
    unsigned int u = __float_as_uint(f);
    return (u & 0x80000000u) ? ~u : (u | 0x80000000u);
}
__device__ __forceinline__ float funkey(unsigned int k) {
    return __uint_as_float((k & 0x80000000u) ? (k ^ 0x80000000u) : ~k);
}

// ---------------- neighbor search: one wave per point (unchanged, passed exact) ----------------
__global__ __launch_bounds__(256) void k_search(const float* __restrict__ xyz,
                                                int* __restrict__ oidx) {
    int wave = (blockIdx.x * 256 + threadIdx.x) >> 6;
    int lane = threadIdx.x & 63;
    int b = wave >> 12;
    int n = wave & (NPTS - 1);
    const float* xb = xyz + (size_t)b * NPTS * 3;
    float cx = xb[n * 3 + 0], cy = xb[n * 3 + 1], cz = xb[n * 3 + 2];
    const float R2 = 0.0256f;
    int cnt = 0;
    int first = 0;
    int* out = oidx + (size_t)wave * KNBR;
    for (int base = 0; base < NPTS; base += 64) {
        #pragma clang fp contract(off)
        int j = base + lane;
        float px = xb[j * 3 + 0], py = xb[j * 3 + 1], pz = xb[j * 3 + 2];
        float dx = px - cx, dy = py - cy, dz = pz - cz;
        float d2 = (dx * dx + dy * dy) + dz * dz;
        bool hit = d2 <= R2;
        unsigned long long m = __ballot(hit);
        if (cnt == 0 && m) first = base + (int)__builtin_ctzll(m);
        if (hit) {
            int pos = cnt + (int)__popcll(m & ((1ull << lane) - 1ull));
            if (pos < KNBR) out[pos] = j;
        }
        cnt += (int)__popcll(m);
        if (cnt >= KNBR) break;
    }
    if (lane >= cnt && lane < KNBR) out[lane] = first;
}

// ---------------- precompute F[j], A[n] (fp16 outputs now) ----------------
__global__ __launch_bounds__(256) void k_prep(const float* __restrict__ xyz,
                                              const float* __restrict__ feat,
                                              const float* __restrict__ W1,
                                              const float* __restrict__ b1,
                                              _Float16* __restrict__ Fh,
                                              _Float16* __restrict__ Ah) {
    __shared__ float featL[8 * 64];
    __shared__ float peL[8 * 96];
    int t = threadIdx.x;
    int g0 = blockIdx.x * 8;
    featL[t]       = feat[(size_t)g0 * 64 + t];
    featL[t + 256] = feat[(size_t)g0 * 64 + t + 256];
    if (t < 96) {
        int a = t >> 5, i = t & 31, fi = i & 15;
        float fr = expf(-0.6140226914650789f * (float)fi);  // ln(1e4)/15
        for (int q = 0; q < 8; q++) {
            float x = xyz[(size_t)(g0 + q) * 3 + a];
            float ang = x * fr;
            peL[q * 96 + t] = (i < 16) ? sinf(ang) : cosf(ang);
        }
    }
    __syncthreads();
    int c = t & 127, qh = t >> 7;
    float fa[4] = {0.f, 0.f, 0.f, 0.f};
    float aa[4] = {0.f, 0.f, 0.f, 0.f};
    for (int f = 0; f < 64; f++) {
        float w = W1[f * TOKC + c];
        #pragma unroll
        for (int q = 0; q < 4; q++) fa[q] += featL[(qh * 4 + q) * 64 + f] * w;
    }
    for (int d = 0; d < 96; d++) {
        float w = W1[(91 + d) * TOKC + c];
        #pragma unroll
        for (int q = 0; q < 4; q++) aa[q] += peL[(qh * 4 + q) * 96 + d] * w;
    }
    float bb = b1[c];
    for (int q = 0; q < 4; q++) {
        size_t g = (size_t)(g0 + qh * 4 + q);
        Fh[g * TOKC + c] = (_Float16)fa[q];
        Ah[g * TOKC + c] = (_Float16)(aa[q] + bb);
    }
}

// ---------------- main: persistent blocks, fp16 MFMA both layers (transposed orientation) ----------------
// h1^T = W1rel^T(A-op, regs) * xin^T(B-op from LDS);  h2^T = W2^T(A-op, regs) * h1^T(B-op from LDS)
// C/D layout: col = lane&15 -> PAIR, row = (lane>>4)*4+reg -> CHANNEL
__global__ __launch_bounds__(256, 2) void k_main(const float* __restrict__ xyz,
                                                 const float* __restrict__ W1,
                                                 const float* __restrict__ W2,
                                                 const int* __restrict__ idxw,
                                                 const _Float16* __restrict__ Fh,
                                                 const _Float16* __restrict__ Ah,
                                                 unsigned int* __restrict__ gmax) {
    __shared__ __align__(16) _Float16 xinL[128 * 40];   // [pair][k32 + pad8]  10 KB
    __shared__ __align__(16) _Float16 hfa[128 * 136];   // [pair][ch128 + pad8] 34.8 KB (F+A, then h1 in-place)
    __shared__ __align__(16) _Float16 arowL[512];       // A+b1 rows for 4 points
    __shared__ int jidxL[128];

    const int t = threadIdx.x;
    const int w = t >> 6, lane = t & 63;
    const int l15 = lane & 15, g = lane >> 4;
    const int b = blockIdx.x >> 8;
    const int pbase = (blockIdx.x & 255) * 16;

    // --- persistent A-operand fragments (loaded once; coalesced 64B segments across l15) ---
    half8 a1[2];        // W1rel^T: ch tile 2w+rt, K=32 (rows 27..31 zero)
    half8 a2[2][4];     // W2^T:    ch tile 2w+rt, kc 0..3
    #pragma unroll
    for (int rt = 0; rt < 2; rt++) {
        int c = 32 * w + 16 * rt + l15;
        #pragma unroll
        for (int j = 0; j < 8; j++) {
            int k = g * 8 + j;
            a1[rt][j] = (k < 27) ? (_Float16)W1[(64 + k) * TOKC + c] : (_Float16)0.f;
        }
        #pragma unroll
        for (int kc = 0; kc < 4; kc++)
            #pragma unroll
            for (int j = 0; j < 8; j++)
                a2[rt][kc][j] = (_Float16)W2[(kc * 32 + g * 8 + j) * TOKC + c];
    }

    float mx[2][4];
    #pragma unroll
    for (int rt = 0; rt < 2; rt++)
        #pragma unroll
        for (int r = 0; r < 4; r++) mx[rt][r] = -1e30f;

    const float FR[4] = {1.f, 0.0464158883f, 0.00215443469f, 1e-4f};  // 10^(-4*fi/3)

    for (int it = 0; it < 4; it++) {
        const int n0 = pbase + it * 4;
        const size_t gp0 = (size_t)b * NPTS + n0;

        // --- stage A: neighbor idx + A-bias rows ---
        if (t < 128) jidxL[t] = idxw[gp0 * KNBR + t];
        {
            const ushort* Ain = (const ushort*)(Ah + gp0 * TOKC);
            ((ushort*)arowL)[t]       = Ain[t];
            ((ushort*)arowL)[t + 256] = Ain[t + 256];
        }
        __syncthreads();

        // --- stage B: xin (rel xyz + rel PE, fp16) + hfa = F[j] + A[n] ---
        if (t < 128) {
            int p = t, n = n0 + (p >> 5), j = jidxL[p];
            const float* xb = xyz + (size_t)b * NPTS * 3;
            float rx = xb[j * 3 + 0] - xb[n * 3 + 0];
            float ry = xb[j * 3 + 1] - xb[n * 3 + 1];
            float rz = xb[j * 3 + 2] - xb[n * 3 + 2];
            float v[32];
            v[0] = rx; v[1] = ry; v[2] = rz;
            float r3[3] = {rx, ry, rz};
            #pragma unroll
            for (int a = 0; a < 3; a++)
                #pragma unroll
                for (int fi = 0; fi < 4; fi++) {
                    float ang = r3[a] * FR[fi];
                    v[3 + a * 8 + fi]     = __sinf(ang);
                    v[3 + a * 8 + 4 + fi] = __cosf(ang);
                }
            #pragma unroll
            for (int i = 27; i < 32; i++) v[i] = 0.f;
            #pragma unroll
            for (int q = 0; q < 4; q++) {
                half8 hv;
                #pragma unroll
                for (int j2 = 0; j2 < 8; j2++) hv[j2] = (_Float16)v[q * 8 + j2];
                *(half8*)&xinL[p * 40 + q * 8] = hv;
            }
        }
        {
            int p = t >> 1, hh = t & 1;
            int j = jidxL[p];
            const half8* fr = (const half8*)(Fh + ((size_t)b * NPTS + j) * TOKC + hh * 64);
            const half8* ar = (const half8*)(arowL + (p >> 5) * TOKC + hh * 64);
            half8* dst = (half8*)(hfa + p * 136 + hh * 64);
            #pragma unroll
            for (int i = 0; i < 8; i++) dst[i] = fr[i] + ar[i];
        }
        __syncthreads();

        // --- phase 1: h1^T = W1rel^T * xin^T, epilogue in-place into hfa (relu(c1 + F + A)) ---
        #pragma unroll
        for (int ct = 0; ct < 8; ct++) {
            int p = ct * 16 + l15;
            half8 bx = *(const half8*)&xinL[p * 40 + g * 8];
            f32x4 z = {0.f, 0.f, 0.f, 0.f};
            f32x4 c1a = __builtin_amdgcn_mfma_f32_16x16x32_f16(a1[0], bx, z, 0, 0, 0);
            f32x4 c1b = __builtin_amdgcn_mfma_f32_16x16x32_f16(a1[1], bx, z, 0, 0, 0);
            #pragma unroll
            for (int rt = 0; rt < 2; rt++) {
                int ch0 = 32 * w + 16 * rt + g * 4;
                half4* hp = (half4*)&hfa[p * 136 + ch0];
                half4 bias = *hp;
                f32x4 cc = rt ? c1b : c1a;
                half4 hv;
                #pragma unroll
                for (int r = 0; r < 4; r++) {
                    float s = cc[r] + (float)bias[r];
                    hv[r] = (_Float16)fmaxf(s, 0.f);
                }
                *hp = hv;
            }
        }
        __syncthreads();

        // --- phase 2: h2^T = W2^T * h1^T, fold max over pairs ---
        f32x4 c2[8][2];
        #pragma unroll
        for (int ct = 0; ct < 8; ct++)
            #pragma unroll
            for (int rt = 0; rt < 2; rt++) {
                f32x4 z = {0.f, 0.f, 0.f, 0.f};
                c2[ct][rt] = z;
            }
        #pragma unroll
        for (int kc = 0; kc < 4; kc++) {
            #pragma unroll
            for (int ct = 0; ct < 8; ct++) {
                half8 bx = *(const half8*)&hfa[(ct * 16 + l15) * 136 + kc * 32 + g * 8];
                c2[ct][0] = __builtin_amdgcn_mfma_f32_16x16x32_f16(a2[0][kc], bx, c2[ct][0], 0, 0, 0);
                c2[ct][1] = __builtin_amdgcn_mfma_f32_16x16x32_f16(a2[1][kc], bx, c2[ct][1], 0, 0, 0);
            }
        }
        #pragma unroll
        for (int ct = 0; ct < 8; ct++)
            #pragma unroll
            for (int rt = 0; rt < 2; rt++)
                #pragma unroll
                for (int r = 0; r < 4; r++)
                    mx[rt][r] = fmaxf(mx[rt][r], c2[ct][rt][r]);
        __syncthreads();   // protect hfa/xin/jidx before next iter's staging
    }

    // --- block-level reduce over the 16 pair-columns, then one atomic per channel ---
    #pragma unroll
    for (int rt = 0; rt < 2; rt++)
        #pragma unroll
        for (int r = 0; r < 4; r++) {
            float v = mx[rt][r];
            #pragma unroll
            for (int off = 1; off < 16; off <<= 1)
                v = fmaxf(v, __shfl_xor(v, off));
            if (l15 == 0) {
                int ch = 32 * w + 16 * rt + g * 4 + r;
                atomicMax(&gmax[b * TOKC + ch], fkey(v));
            }
        }
}

// ---------------- final tiny MLP ----------------
__global__ __launch_bounds__(128) void k_final(const unsigned int* __restrict__ gmax,
                                               const float* __restrict__ b2,
                                               const float* __restrict__ W3,
                                               const float* __restrict__ b3,
                                               const float* __restrict__ W4,
                                               const float* __restrict__ b4,
                                               float* __restrict__ out) {
    __shared__ float gl[128], sl[128];
    int b = blockIdx.x, c = threadIdx.x;
    gl[c] = funkey(gmax[b * TOKC + c]) + b2[c];
    __syncthreads();
    float s = b3[c];
    for (int k = 0; k < 128; k++) s += gl[k] * W3[k * TOKC + c];
    sl[c] = fmaxf(s, 0.f);
    __syncthreads();
    float o = b4[c];
    for (int k = 0; k < 128; k++) o += sl[k] * W4[k * TOKC + c];
    out[b * TOKC + c] = o;
}

extern "C" void kernel_launch(void* const* d_in, const int* in_sizes, int n_in,
                              void* d_out, int out_size, void* d_ws, size_t ws_size,
                              hipStream_t stream) {
    const float* xyz  = (const float*)d_in[0];
    const float* feat = (const float*)d_in[1];
    const float* W1   = (const float*)d_in[2];
    const float* b1   = (const float*)d_in[3];
    const float* W2   = (const float*)d_in[4];
    const float* b2   = (const float*)d_in[5];
    const float* W3   = (const float*)d_in[6];
    const float* b3   = (const float*)d_in[7];
    const float* W4   = (const float*)d_in[8];
    const float* b4   = (const float*)d_in[9];

    char* ws = (char*)d_ws;
    int*          idxw = (int*)ws;
    _Float16*     Fh   = (_Float16*)(ws + OFF_FH);
    _Float16*     Ah   = (_Float16*)(ws + OFF_AH);
    unsigned int* gmax = (unsigned int*)(ws + OFF_GMAX);

    hipMemsetAsync(gmax, 0, BATCH * TOKC * sizeof(unsigned int), stream);
    k_search<<<dim3((BATCH * NPTS) / 4), dim3(256), 0, stream>>>(xyz, idxw);
    k_prep<<<dim3((BATCH * NPTS) / 8), dim3(256), 0, stream>>>(xyz, feat, W1, b1, Fh, Ah);
    k_main<<<dim3(512), dim3(256), 0, stream>>>(xyz, W1, W2, idxw, Fh, Ah, gmax);
    k_final<<<dim3(BATCH), dim3(128), 0, stream>>>(gmax, b2, W3, b3, W4, b4, (float*)d_out);
}

// Round 4
// 159.110 us; speedup vs baseline: 4.4251x; 1.3917x over previous
//
#include <hip/hip_runtime.h>
#include <stdint.h>

#define BATCH 2
#define NPTS  4096
#define KNBR  32
#define TOKC  128

typedef _Float16 half8 __attribute__((ext_vector_type(8)));
typedef _Float16 half4 __attribute__((ext_vector_type(4)));
typedef float    f32x4 __attribute__((ext_vector_type(4)));

// ---------------- workspace layout (bytes) ----------------
#define OFF_FH   (1u << 20)
#define OFF_AH   (3u << 20)
#define OFF_GMAX (5u << 20)

__device__ __forceinline__ unsigned int fkey(float f) {
    unsigned int u = __float_as_uint(f);
    return (u & 0x80000000u) ? ~u : (u | 0x80000000u);
}
__device__ __forceinline__ float funkey(unsigned int k) {
    return __uint_as_float((k & 0x80000000u) ? (k ^ 0x80000000u) : ~k);
}

// ---------------- neighbor search: one wave per point, next-chunk prefetch ----------------
__global__ __launch_bounds__(256) void k_search(const float* __restrict__ xyz,
                                                int* __restrict__ oidx) {
    int wave = (blockIdx.x * 256 + threadIdx.x) >> 6;
    int lane = threadIdx.x & 63;
    int b = wave >> 12;
    int n = wave & (NPTS - 1);
    const float* xb = xyz + (size_t)b * NPTS * 3;
    float cx = xb[n * 3 + 0], cy = xb[n * 3 + 1], cz = xb[n * 3 + 2];
    const float R2 = 0.0256f;
    int cnt = 0;
    int first = 0;
    int* out = oidx + (size_t)wave * KNBR;
    // prefetch chunk 0
    float px = xb[lane * 3 + 0], py = xb[lane * 3 + 1], pz = xb[lane * 3 + 2];
    for (int base = 0; base < NPTS; base += 64) {
        #pragma clang fp contract(off)
        float dx = px - cx, dy = py - cy, dz = pz - cz;
        float d2 = (dx * dx + dy * dy) + dz * dz;   // same order as numpy, no fma
        bool hit = d2 <= R2;
        // prefetch next chunk (wraps at end; issues before the ballot/branch chain)
        int jn = ((base + 64) & (NPTS - 1)) + lane;
        float nx = xb[jn * 3 + 0], ny = xb[jn * 3 + 1], nz = xb[jn * 3 + 2];
        unsigned long long m = __ballot(hit);
        if (cnt == 0 && m) first = base + (int)__builtin_ctzll(m);
        if (hit) {
            int pos = cnt + (int)__popcll(m & ((1ull << lane) - 1ull));
            if (pos < KNBR) out[pos] = base + lane;
        }
        cnt += (int)__popcll(m);
        if (cnt >= KNBR) break;
        px = nx; py = ny; pz = nz;
    }
    if (lane >= cnt && lane < KNBR) out[lane] = first;
}

// ---------------- precompute F[j], A[n] via MFMA (same orientation as k_main) ----------------
// out^T = W1part^T (A-op, regs) * in^T (B-op, LDS); C/D: col=lane&15 -> point, row=(lane>>4)*4+reg -> ch
__global__ __launch_bounds__(256) void k_prep(const float* __restrict__ xyz,
                                              const float* __restrict__ feat,
                                              const float* __restrict__ W1,
                                              const float* __restrict__ b1,
                                              _Float16* __restrict__ Fh,
                                              _Float16* __restrict__ Ah) {
    __shared__ __align__(16) _Float16 inL[16][168];   // k: 0..63 feat, 64..159 abs-pe, +8 pad
    const int t = threadIdx.x;
    const int w = t >> 6, lane = t & 63;
    const int l15 = lane & 15, g = lane >> 4;
    const int g0 = blockIdx.x * 16;                   // flat point base (b*N+n)

    // A-operand fragments: column c = 32w+16rt+l15, k = kc*32 + g*8 + j
    half8 af[2][2];   // W1 rows 0..63   (neighbor-feature part)
    half8 ap[2][3];   // W1 rows 91..186 (abs-pe part)
    float4 b1v[2];
    #pragma unroll
    for (int rt = 0; rt < 2; rt++) {
        int c = 32 * w + 16 * rt + l15;
        #pragma unroll
        for (int kc = 0; kc < 2; kc++)
            #pragma unroll
            for (int j = 0; j < 8; j++)
                af[rt][kc][j] = (_Float16)W1[(kc * 32 + g * 8 + j) * TOKC + c];
        #pragma unroll
        for (int kc = 0; kc < 3; kc++)
            #pragma unroll
            for (int j = 0; j < 8; j++)
                ap[rt][kc][j] = (_Float16)W1[(91 + kc * 32 + g * 8 + j) * TOKC + c];
        b1v[rt] = *(const float4*)&b1[32 * w + 16 * rt + g * 4];
    }

    // stage feat (16 pts x 64 ch fp32 -> fp16): one float4 per thread
    {
        float4 v = ((const float4*)(feat + (size_t)g0 * 64))[t];
        half4 hv = {(_Float16)v.x, (_Float16)v.y, (_Float16)v.z, (_Float16)v.w};
        *(half4*)&inL[t >> 4][(t & 15) * 4] = hv;
    }
    // stage abs-pe (16 pts x 96): 6 values per thread
    {
        int p = t >> 4, v0 = (t & 15) * 6;
        const float* xp = xyz + (size_t)(g0 + p) * 3;
        #pragma unroll
        for (int u = 0; u < 6; u++) {
            int d = v0 + u;                 // 0..95
            int a = d >> 5, i = d & 31, fi = i & 15;
            float fr = __expf(-0.6140226914650789f * (float)fi);  // ln(1e4)/15
            float ang = xp[a] * fr;
            inL[p][64 + d] = (_Float16)((i < 16) ? __sinf(ang) : __cosf(ang));
        }
    }
    __syncthreads();

    f32x4 cF[2], cA[2];
    #pragma unroll
    for (int rt = 0; rt < 2; rt++) { f32x4 z = {0.f, 0.f, 0.f, 0.f}; cF[rt] = z; cA[rt] = z; }
    #pragma unroll
    for (int kc = 0; kc < 2; kc++) {
        half8 bx = *(const half8*)&inL[l15][kc * 32 + g * 8];
        cF[0] = __builtin_amdgcn_mfma_f32_16x16x32_f16(af[0][kc], bx, cF[0], 0, 0, 0);
        cF[1] = __builtin_amdgcn_mfma_f32_16x16x32_f16(af[1][kc], bx, cF[1], 0, 0, 0);
    }
    #pragma unroll
    for (int kc = 0; kc < 3; kc++) {
        half8 bx = *(const half8*)&inL[l15][64 + kc * 32 + g * 8];
        cA[0] = __builtin_amdgcn_mfma_f32_16x16x32_f16(ap[0][kc], bx, cA[0], 0, 0, 0);
        cA[1] = __builtin_amdgcn_mfma_f32_16x16x32_f16(ap[1][kc], bx, cA[1], 0, 0, 0);
    }

    size_t pbase = ((size_t)g0 + l15) * TOKC;
    #pragma unroll
    for (int rt = 0; rt < 2; rt++) {
        int ch0 = 32 * w + 16 * rt + g * 4;
        half4 fv, av;
        #pragma unroll
        for (int r = 0; r < 4; r++) {
            fv[r] = (_Float16)cF[rt][r];
            av[r] = (_Float16)(cA[rt][r] + b1v[rt][r]);
        }
        *(half4*)&Fh[pbase + ch0] = fv;
        *(half4*)&Ah[pbase + ch0] = av;
    }
}

// ---------------- main: persistent blocks, fp16 MFMA both layers (unchanged from round 2) ----------------
__global__ __launch_bounds__(256, 2) void k_main(const float* __restrict__ xyz,
                                                 const float* __restrict__ W1,
                                                 const float* __restrict__ W2,
                                                 const int* __restrict__ idxw,
                                                 const _Float16* __restrict__ Fh,
                                                 const _Float16* __restrict__ Ah,
                                                 unsigned int* __restrict__ gmax) {
    __shared__ __align__(16) _Float16 xinL[128 * 40];
    __shared__ __align__(16) _Float16 hfa[128 * 136];
    __shared__ __align__(16) _Float16 arowL[512];
    __shared__ int jidxL[128];

    const int t = threadIdx.x;
    const int w = t >> 6, lane = t & 63;
    const int l15 = lane & 15, g = lane >> 4;
    const int b = blockIdx.x >> 8;
    const int pbase = (blockIdx.x & 255) * 16;

    half8 a1[2];
    half8 a2[2][4];
    #pragma unroll
    for (int rt = 0; rt < 2; rt++) {
        int c = 32 * w + 16 * rt + l15;
        #pragma unroll
        for (int j = 0; j < 8; j++) {
            int k = g * 8 + j;
            a1[rt][j] = (k < 27) ? (_Float16)W1[(64 + k) * TOKC + c] : (_Float16)0.f;
        }
        #pragma unroll
        for (int kc = 0; kc < 4; kc++)
            #pragma unroll
            for (int j = 0; j < 8; j++)
                a2[rt][kc][j] = (_Float16)W2[(kc * 32 + g * 8 + j) * TOKC + c];
    }

    float mx[2][4];
    #pragma unroll
    for (int rt = 0; rt < 2; rt++)
        #pragma unroll
        for (int r = 0; r < 4; r++) mx[rt][r] = -1e30f;

    const float FR[4] = {1.f, 0.0464158883f, 0.00215443469f, 1e-4f};

    for (int it = 0; it < 4; it++) {
        const int n0 = pbase + it * 4;
        const size_t gp0 = (size_t)b * NPTS + n0;

        if (t < 128) jidxL[t] = idxw[gp0 * KNBR + t];
        {
            const ushort* Ain = (const ushort*)(Ah + gp0 * TOKC);
            ((ushort*)arowL)[t]       = Ain[t];
            ((ushort*)arowL)[t + 256] = Ain[t + 256];
        }
        __syncthreads();

        if (t < 128) {
            int p = t, n = n0 + (p >> 5), j = jidxL[p];
            const float* xb = xyz + (size_t)b * NPTS * 3;
            float rx = xb[j * 3 + 0] - xb[n * 3 + 0];
            float ry = xb[j * 3 + 1] - xb[n * 3 + 1];
            float rz = xb[j * 3 + 2] - xb[n * 3 + 2];
            float v[32];
            v[0] = rx; v[1] = ry; v[2] = rz;
            float r3[3] = {rx, ry, rz};
            #pragma unroll
            for (int a = 0; a < 3; a++)
                #pragma unroll
                for (int fi = 0; fi < 4; fi++) {
                    float ang = r3[a] * FR[fi];
                    v[3 + a * 8 + fi]     = __sinf(ang);
                    v[3 + a * 8 + 4 + fi] = __cosf(ang);
                }
            #pragma unroll
            for (int i = 27; i < 32; i++) v[i] = 0.f;
            #pragma unroll
            for (int q = 0; q < 4; q++) {
                half8 hv;
                #pragma unroll
                for (int j2 = 0; j2 < 8; j2++) hv[j2] = (_Float16)v[q * 8 + j2];
                *(half8*)&xinL[p * 40 + q * 8] = hv;
            }
        }
        {
            int p = t >> 1, hh = t & 1;
            int j = jidxL[p];
            const half8* fr = (const half8*)(Fh + ((size_t)b * NPTS + j) * TOKC + hh * 64);
            const half8* ar = (const half8*)(arowL + (p >> 5) * TOKC + hh * 64);
            half8* dst = (half8*)(hfa + p * 136 + hh * 64);
            #pragma unroll
            for (int i = 0; i < 8; i++) dst[i] = fr[i] + ar[i];
        }
        __syncthreads();

        #pragma unroll
        for (int ct = 0; ct < 8; ct++) {
            int p = ct * 16 + l15;
            half8 bx = *(const half8*)&xinL[p * 40 + g * 8];
            f32x4 z = {0.f, 0.f, 0.f, 0.f};
            f32x4 c1a = __builtin_amdgcn_mfma_f32_16x16x32_f16(a1[0], bx, z, 0, 0, 0);
            f32x4 c1b = __builtin_amdgcn_mfma_f32_16x16x32_f16(a1[1], bx, z, 0, 0, 0);
            #pragma unroll
            for (int rt = 0; rt < 2; rt++) {
                int ch0 = 32 * w + 16 * rt + g * 4;
                half4* hp = (half4*)&hfa[p * 136 + ch0];
                half4 bias = *hp;
                f32x4 cc = rt ? c1b : c1a;
                half4 hv;
                #pragma unroll
                for (int r = 0; r < 4; r++) {
                    float s = cc[r] + (float)bias[r];
                    hv[r] = (_Float16)fmaxf(s, 0.f);
                }
                *hp = hv;
            }
        }
        __syncthreads();

        f32x4 c2[8][2];
        #pragma unroll
        for (int ct = 0; ct < 8; ct++)
            #pragma unroll
            for (int rt = 0; rt < 2; rt++) {
                f32x4 z = {0.f, 0.f, 0.f, 0.f};
                c2[ct][rt] = z;
            }
        #pragma unroll
        for (int kc = 0; kc < 4; kc++) {
            #pragma unroll
            for (int ct = 0; ct < 8; ct++) {
                half8 bx = *(const half8*)&hfa[(ct * 16 + l15) * 136 + kc * 32 + g * 8];
                c2[ct][0] = __builtin_amdgcn_mfma_f32_16x16x32_f16(a2[0][kc], bx, c2[ct][0], 0, 0, 0);
                c2[ct][1] = __builtin_amdgcn_mfma_f32_16x16x32_f16(a2[1][kc], bx, c2[ct][1], 0, 0, 0);
            }
        }
        #pragma unroll
        for (int ct = 0; ct < 8; ct++)
            #pragma unroll
            for (int rt = 0; rt < 2; rt++)
                #pragma unroll
                for (int r = 0; r < 4; r++)
                    mx[rt][r] = fmaxf(mx[rt][r], c2[ct][rt][r]);
        __syncthreads();
    }

    #pragma unroll
    for (int rt = 0; rt < 2; rt++)
        #pragma unroll
        for (int r = 0; r < 4; r++) {
            float v = mx[rt][r];
            #pragma unroll
            for (int off = 1; off < 16; off <<= 1)
                v = fmaxf(v, __shfl_xor(v, off));
            if (l15 == 0) {
                int ch = 32 * w + 16 * rt + g * 4 + r;
                atomicMax(&gmax[b * TOKC + ch], fkey(v));
            }
        }
}

// ---------------- final tiny MLP ----------------
__global__ __launch_bounds__(128) void k_final(const unsigned int* __restrict__ gmax,
                                               const float* __restrict__ b2,
                                               const float* __restrict__ W3,
                                               const float* __restrict__ b3,
                                               const float* __restrict__ W4,
                                               const float* __restrict__ b4,
                                               float* __restrict__ out) {
    __shared__ float gl[128], sl[128];
    int b = blockIdx.x, c = threadIdx.x;
    gl[c] = funkey(gmax[b * TOKC + c]) + b2[c];
    __syncthreads();
    float s = b3[c];
    for (int k = 0; k < 128; k++) s += gl[k] * W3[k * TOKC + c];
    sl[c] = fmaxf(s, 0.f);
    __syncthreads();
    float o = b4[c];
    for (int k = 0; k < 128; k++) o += sl[k] * W4[k * TOKC + c];
    out[b * TOKC + c] = o;
}

extern "C" void kernel_launch(void* const* d_in, const int* in_sizes, int n_in,
                              void* d_out, int out_size, void* d_ws, size_t ws_size,
                              hipStream_t stream) {
    const float* xyz  = (const float*)d_in[0];
    const float* feat = (const float*)d_in[1];
    const float* W1   = (const float*)d_in[2];
    const float* b1   = (const float*)d_in[3];
    const float* W2   = (const float*)d_in[4];
    const float* b2   = (const float*)d_in[5];
    const float* W3   = (const float*)d_in[6];
    const float* b3   = (const float*)d_in[7];
    const float* W4   = (const float*)d_in[8];
    const float* b4   = (const float*)d_in[9];

    char* ws = (char*)d_ws;
    int*          idxw = (int*)ws;
    _Float16*     Fh   = (_Float16*)(ws + OFF_FH);
    _Float16*     Ah   = (_Float16*)(ws + OFF_AH);
    unsigned int* gmax = (unsigned int*)(ws + OFF_GMAX);

    (void)hipMemsetAsync(gmax, 0, BATCH * TOKC * sizeof(unsigned int), stream);
    k_search<<<dim3((BATCH * NPTS) / 4), dim3(256), 0, stream>>>(xyz, idxw);
    k_prep<<<dim3((BATCH * NPTS) / 16), dim3(256), 0, stream>>>(xyz, feat, W1, b1, Fh, Ah);
    k_main<<<dim3(512), dim3(256), 0, stream>>>(xyz, W1, W2, idxw, Fh, Ah, gmax);
    k_final<<<dim3(BATCH), dim3(128), 0, stream>>>(gmax, b2, W3, b3, W4, b4, (float*)d_out);
}